// Round 1
// baseline (280.479 us; speedup 1.0000x reference)
//
#include <hip/hip_runtime.h>
#include <cmath>
#include <complex>

#define FEAT 576

typedef _Float16 f16;
typedef _Float16 f16x8 __attribute__((ext_vector_type(8)));
typedef float f32x4 __attribute__((ext_vector_type(4)));

struct KC { float c[363]; };

// ---------------- Wigner-3j nonzero patterns (compile-time) ----------------
__host__ __device__ constexpr bool nz112(int i, int j, int k) {
  return (k == 0) ? ((i == 2 && j == 0) || (i == 0 && j == 2))
       : (k == 1) ? ((i == 0 && j == 1) || (i == 1 && j == 0))
       : (k == 2) ? (i == j)
       : (k == 3) ? ((i == 1 && j == 2) || (i == 2 && j == 1))
       :            ((i == 0 && j == 0) || (i == 2 && j == 2));
}
__host__ __device__ constexpr bool nz222(int i, int j, int k) {
  return (k == 0) ? ((i == 1 && j == 3) || (i == 3 && j == 1) || (i == 0 && j == 2) || (i == 2 && j == 0))
       : (k == 1) ? ((i == 0 && j == 3) || (i == 3 && j == 0) || (i == 1 && j == 2) || (i == 2 && j == 1) || (i == 1 && j == 4) || (i == 4 && j == 1))
       : (k == 2) ? (i == j)
       : (k == 3) ? ((i == 0 && j == 1) || (i == 1 && j == 0) || (i == 3 && j == 2) || (i == 2 && j == 3) || (i == 3 && j == 4) || (i == 4 && j == 3))
       :            ((i == 1 && j == 1) || (i == 3 && j == 3) || (i == 2 && j == 4) || (i == 4 && j == 2));
}
__host__ __device__ constexpr bool w3j_nz(int l1, int l2, int l3, int i, int j, int k) {
  return (l1 == 0) ? (j == k)
       : (l2 == 0) ? (i == k)
       : (l3 == 0) ? (i == j)
       : (l1 == 1 && l2 == 1 && l3 == 2) ? nz112(i, j, k)
       : (l1 == 1 && l2 == 2 && l3 == 1) ? nz112(i, k, j)
       : (l1 == 2 && l2 == 1 && l3 == 1) ? nz112(j, k, i)
       : nz222(i, j, k);
}

// ---------------- prep: ws f32 -> f16 in MFMA B-fragment order ----------------
// layout: wsf[((p*4 + ntile)*128 + uk)*512 + lane*8 + j]
//   = ws[p][uv = uk*32 + (lane>>4)*8 + j][w = ntile*16 + (lane&15)]
__global__ void prep_ws(const float* __restrict__ ws, f16* __restrict__ wsf) {
  int blk = blockIdx.x;            // 11*128 blocks
  int p = blk >> 7, uk = blk & 127;
  int tid = threadIdx.x;           // 256
  int nt = tid >> 6, l = tid & 63;
  int w = nt * 16 + (l & 15);
  int uvb = uk * 32 + (l >> 4) * 8;
  f16x8 v;
#pragma unroll
  for (int j = 0; j < 8; ++j)
    v[j] = (f16)ws[(size_t)p * 262144 + (size_t)(uvb + j) * 64 + w];
  *(f16x8*)(wsf + ((size_t)((p * 4 + nt) * 128 + uk)) * 512 + (size_t)l * 8) = v;
}

// ---------------- main kernel ----------------
__device__ __forceinline__ f32x4 mfma16(f16x8 a, f16x8 b, f32x4 c) {
  return __builtin_amdgcn_mfma_f32_16x16x32_f16(a, b, c, 0, 0, 0);
}

template <int L1, int L2, int L3, int PORIG, int COFF>
__device__ __forceinline__ void process_path(
    const float* __restrict__ x1, const float* __restrict__ x2,
    const f16* __restrict__ wsf, const KC& kc, float* sbuf,
    int b0, int tid, int lane, int nt, int bh, f32x4 (&o)[5]) {
  constexpr int d1 = 2 * L1 + 1, d2 = 2 * L2 + 1, d3 = 2 * L3 + 1;
  constexpr int OFF1 = (L1 == 0) ? 0 : (L1 == 1) ? 64 : 256;
  constexpr int OFF2 = (L2 == 0) ? 0 : (L2 == 1) ? 64 : 256;
  const int brow = lane >> 4, bcol = lane & 15;

  // ---- stage x2 irrep slice into LDS (sbuf reused) ----
  __syncthreads();  // protect sbuf from previous path's readers
  for (int idx = tid; idx < 32 * 64 * d2; idx += 512) {
    int b = idx / (64 * d2), f = idx - b * (64 * d2);  // f = v*d2 + jj
    sbuf[f * 36 + b] = x2[(size_t)(b0 + b) * FEAT + OFF2 + f];
  }
  __syncthreads();

  // ---- pack x2 A-fragments (persist in registers for all 64 u) ----
  f16x8 afrag[d2][2];
#pragma unroll
  for (int jj = 0; jj < d2; ++jj)
#pragma unroll
    for (int ks = 0; ks < 2; ++ks)
#pragma unroll
      for (int j = 0; j < 8; ++j) {
        int v = ks * 32 + brow * 8 + j;
        afrag[jj][ks][j] = (f16)sbuf[(v * d2 + jj) * 36 + bh * 16 + bcol];
      }
  __syncthreads();

  // ---- stage x1 irrep slice into LDS: [u][i][36 pad] ----
  for (int idx = tid; idx < 32 * 64 * d1; idx += 512) {
    int b = idx / (64 * d1), f = idx - b * (64 * d1);  // f = u*d1 + i
    sbuf[f * 36 + b] = x1[(size_t)(b0 + b) * FEAT + OFF1 + f];
  }
  __syncthreads();

  // ---- u loop: MFMA M_u = x2 @ ws_u, then C-mix into o ----
  const f16* wb = wsf + ((size_t)(PORIG * 4 + nt)) * 128 * 512 + (size_t)lane * 8;

  auto load_bf = [&](f16x8(&bfr)[2], int u) {
    bfr[0] = *(const f16x8*)(wb + (size_t)(u * 2 + 0) * 512);
    bfr[1] = *(const f16x8*)(wb + (size_t)(u * 2 + 1) * 512);
  };
  auto step = [&](int u, f16x8(&bfr)[2]) {
    f32x4 M[d2];
#pragma unroll
    for (int jj = 0; jj < d2; ++jj) {
      f32x4 z = {0.f, 0.f, 0.f, 0.f};
      M[jj] = mfma16(afrag[jj][0], bfr[0], z);
    }
#pragma unroll
    for (int jj = 0; jj < d2; ++jj)
      M[jj] = mfma16(afrag[jj][1], bfr[1], M[jj]);
    f32x4 xv[d1];
#pragma unroll
    for (int i = 0; i < d1; ++i)
      xv[i] = *(const f32x4*)&sbuf[(u * d1 + i) * 36 + bh * 16 + brow * 4];
#pragma unroll
    for (int k3 = 0; k3 < d3; ++k3)
#pragma unroll
      for (int i = 0; i < d1; ++i)
#pragma unroll
        for (int jj = 0; jj < d2; ++jj) {
          if (w3j_nz(L1, L2, L3, i, jj, k3)) {
            float cv = kc.c[COFF + (i * d2 + jj) * d3 + k3];
#pragma unroll
            for (int r = 0; r < 4; ++r)
              o[k3][r] += (cv * xv[i][r]) * M[jj][r];
          }
        }
  };

  f16x8 bfA[2], bfB[2], bfC[2], bfD[2];
  load_bf(bfA, 0); load_bf(bfB, 1); load_bf(bfC, 2); load_bf(bfD, 3);
#pragma unroll 1
  for (int ug = 0; ug < 16; ++ug) {
    int u4 = ug * 4;
    bool pr = (ug < 15);
    step(u4 + 0, bfA); if (pr) load_bf(bfA, u4 + 4);
    step(u4 + 1, bfB); if (pr) load_bf(bfB, u4 + 5);
    step(u4 + 2, bfC); if (pr) load_bf(bfC, u4 + 6);
    step(u4 + 3, bfD); if (pr) load_bf(bfD, u4 + 7);
  }
}

template <int L3, int OFF3>
__device__ __forceinline__ void store_group(float* __restrict__ out, int b0, int lane,
                                            int nt, int bh, f32x4 (&o)[5]) {
  constexpr int d3 = 2 * L3 + 1;
  const int brow = lane >> 4, bcol = lane & 15;
#pragma unroll
  for (int k3 = 0; k3 < d3; ++k3)
#pragma unroll
    for (int r = 0; r < 4; ++r)
      out[(size_t)(b0 + bh * 16 + brow * 4 + r) * FEAT + OFF3 + (nt * 16 + bcol) * d3 + k3] = o[k3][r];
#pragma unroll
  for (int k3 = 0; k3 < 5; ++k3) o[k3] = f32x4{0.f, 0.f, 0.f, 0.f};
}

__global__ __launch_bounds__(512, 2) void tp_main(
    const float* __restrict__ x1, const float* __restrict__ x2,
    const f16* __restrict__ wsf, float* __restrict__ out, KC kc) {
  __shared__ float sbuf[64 * 5 * 36];
  int tid = threadIdx.x;
  int lane = tid & 63, wave = tid >> 6;
  int nt = wave & 3, bh = wave >> 2;
  int b0 = blockIdx.x * 32;
  f32x4 o[5];
#pragma unroll
  for (int k = 0; k < 5; ++k) o[k] = f32x4{0.f, 0.f, 0.f, 0.f};

  // i3 = 0 group (out feats [0,64), d3=1)
  process_path<0, 0, 0, 0, 0>(x1, x2, wsf, kc, sbuf, b0, tid, lane, nt, bh, o);
  process_path<1, 1, 0, 4, 44>(x1, x2, wsf, kc, sbuf, b0, tid, lane, nt, bh, o);
  process_path<2, 2, 0, 9, 213>(x1, x2, wsf, kc, sbuf, b0, tid, lane, nt, bh, o);
  store_group<0, 0>(out, b0, lane, nt, bh, o);
  // i3 = 1 group (out feats [64,256), d3=3)
  process_path<0, 1, 1, 1, 1>(x1, x2, wsf, kc, sbuf, b0, tid, lane, nt, bh, o);
  process_path<1, 0, 1, 3, 35>(x1, x2, wsf, kc, sbuf, b0, tid, lane, nt, bh, o);
  process_path<1, 2, 1, 6, 98>(x1, x2, wsf, kc, sbuf, b0, tid, lane, nt, bh, o);
  process_path<2, 1, 1, 8, 168>(x1, x2, wsf, kc, sbuf, b0, tid, lane, nt, bh, o);
  store_group<1, 64>(out, b0, lane, nt, bh, o);
  // i3 = 2 group (out feats [256,576), d3=5)
  process_path<0, 2, 2, 2, 10>(x1, x2, wsf, kc, sbuf, b0, tid, lane, nt, bh, o);
  process_path<1, 1, 2, 5, 53>(x1, x2, wsf, kc, sbuf, b0, tid, lane, nt, bh, o);
  process_path<2, 0, 2, 7, 143>(x1, x2, wsf, kc, sbuf, b0, tid, lane, nt, bh, o);
  process_path<2, 2, 2, 10, 238>(x1, x2, wsf, kc, sbuf, b0, tid, lane, nt, bh, o);
  store_group<2, 256>(out, b0, lane, nt, bh, o);
}

// ---------------- host: exact port of reference Wigner-3j construction ----------------
static double factd(int n) { double r = 1; for (int i = 2; i <= n; ++i) r *= i; return r; }

static double su2_cg(int j1, int j2, int j3, int m1, int m2, int m3) {
  if (m1 + m2 != m3) return 0.0;
  double pre = std::sqrt((2 * j3 + 1) * factd(j1 + j2 - j3) * factd(j1 - j2 + j3) * factd(-j1 + j2 + j3) / factd(j1 + j2 + j3 + 1));
  pre *= std::sqrt(factd(j3 + m3) * factd(j3 - m3) * factd(j1 - m1) * factd(j1 + m1) * factd(j2 - m2) * factd(j2 + m2));
  double s = 0.0;
  for (int v = 0; v <= j1 + j2 - j3; ++v) {
    int t[6] = {v, j1 + j2 - j3 - v, j1 - m1 - v, j2 + m2 - v, j3 - j2 + m1 + v, j3 - j1 - m2 + v};
    bool ok = true;
    for (int x = 0; x < 6; ++x) if (t[x] < 0) ok = false;
    if (!ok) continue;
    double den = 1.0;
    for (int x = 0; x < 6; ++x) den *= factd(t[x]);
    s += ((v & 1) ? -1.0 : 1.0) / den;
  }
  return pre * s;
}

static void qmat(int l, std::complex<double> q[5][5]) {
  int n = 2 * l + 1;
  for (int i = 0; i < 5; ++i) for (int j = 0; j < 5; ++j) q[i][j] = 0.0;
  const double s = 1.0 / std::sqrt(2.0);
  for (int m = -l; m < 0; ++m) {
    q[l + m][l - m] = s;                             // col l+|m|
    q[l + m][l + m] = std::complex<double>(0.0, -s); // col l-|m|
  }
  q[l][l] = 1.0;
  for (int m = 1; m <= l; ++m) {
    double sg = (m % 2) ? -1.0 : 1.0;
    q[l + m][l + m] = sg * s;
    q[l + m][l - m] = std::complex<double>(0.0, sg * s);
  }
  std::complex<double> pref(1.0, 0.0);
  for (int t = 0; t < l; ++t) pref *= std::complex<double>(0.0, -1.0);
  for (int i = 0; i < n; ++i) for (int j = 0; j < n; ++j) q[i][j] *= pref;
}

static void compute_w3j(int l1, int l2, int l3, float* dst) {
  int n1 = 2 * l1 + 1, n2 = 2 * l2 + 1, n3 = 2 * l3 + 1;
  std::complex<double> q1[5][5], q2[5][5], q3[5][5];
  qmat(l1, q1); qmat(l2, q2); qmat(l3, q3);
  double C[5][5][5];
  double nrm = 0.0;
  for (int a = 0; a < n1; ++a)
    for (int b = 0; b < n2; ++b)
      for (int c = 0; c < n3; ++c) {
        std::complex<double> acc(0.0, 0.0);
        for (int i = 0; i < n1; ++i)
          for (int j = 0; j < n2; ++j)
            for (int k = 0; k < n3; ++k) {
              double cg = su2_cg(l1, l2, l3, i - l1, j - l2, k - l3);
              if (cg != 0.0) acc += q1[i][a] * q2[j][b] * std::conj(q3[k][c]) * cg;
            }
        C[a][b][c] = acc.real();
        nrm += acc.real() * acc.real();
      }
  double inv = 1.0 / std::sqrt(nrm);
  for (int a = 0; a < n1; ++a)
    for (int b = 0; b < n2; ++b)
      for (int c = 0; c < n3; ++c)
        dst[(a * n2 + b) * n3 + c] = (float)(C[a][b][c] * inv);
}

extern "C" void kernel_launch(void* const* d_in, const int* in_sizes, int n_in,
                              void* d_out, int out_size, void* d_ws, size_t ws_size,
                              hipStream_t stream) {
  const float* x1 = (const float*)d_in[0];
  const float* x2 = (const float*)d_in[1];
  const float* ws = (const float*)d_in[2];
  float* out = (float*)d_out;
  f16* wsf = (f16*)d_ws;

  KC kc;
  {
    static const int L1[11] = {0, 0, 0, 1, 1, 1, 1, 2, 2, 2, 2};
    static const int L2[11] = {0, 1, 2, 0, 1, 1, 2, 0, 1, 2, 2};
    static const int L3[11] = {0, 1, 2, 1, 0, 2, 1, 2, 1, 0, 2};
    static const int COFFS[11] = {0, 1, 10, 35, 44, 53, 98, 143, 168, 213, 238};
    for (int p = 0; p < 11; ++p) compute_w3j(L1[p], L2[p], L3[p], kc.c + COFFS[p]);
  }

  hipLaunchKernelGGL(prep_ws, dim3(11 * 128), dim3(256), 0, stream, ws, wsf);
  hipLaunchKernelGGL(tp_main, dim3(128), dim3(512), 0, stream, x1, x2, wsf, out, kc);
}

// Round 3
// 183.359 us; speedup vs baseline: 1.5297x; 1.5297x over previous
//
#include <hip/hip_runtime.h>
#include <cmath>
#include <complex>

#define FEAT 576
#define PAD1 36
#define PAD2 35

typedef _Float16 f16;
typedef _Float16 f16x2 __attribute__((ext_vector_type(2)));
typedef _Float16 f16x4 __attribute__((ext_vector_type(4)));
typedef _Float16 f16x8 __attribute__((ext_vector_type(8)));
typedef float f32x4 __attribute__((ext_vector_type(4)));

struct KC { float c[363]; };

// pack two f32 -> f16x2 with one v_cvt_pkrtz (bit_cast bridges __fp16/_Float16 vec types)
__device__ __forceinline__ f16x2 pkrtz(float a, float b) {
  auto t = __builtin_amdgcn_cvt_pkrtz(a, b);
  return __builtin_bit_cast(f16x2, t);
}

// ---------------- Wigner-3j nonzero patterns (compile-time) ----------------
__host__ __device__ constexpr bool nz112(int i, int j, int k) {
  return (k == 0) ? ((i == 2 && j == 0) || (i == 0 && j == 2))
       : (k == 1) ? ((i == 0 && j == 1) || (i == 1 && j == 0))
       : (k == 2) ? (i == j)
       : (k == 3) ? ((i == 1 && j == 2) || (i == 2 && j == 1))
       :            ((i == 0 && j == 0) || (i == 2 && j == 2));
}
__host__ __device__ constexpr bool nz222(int i, int j, int k) {
  return (k == 0) ? ((i == 1 && j == 3) || (i == 3 && j == 1) || (i == 0 && j == 2) || (i == 2 && j == 0))
       : (k == 1) ? ((i == 0 && j == 3) || (i == 3 && j == 0) || (i == 1 && j == 2) || (i == 2 && j == 1) || (i == 1 && j == 4) || (i == 4 && j == 1))
       : (k == 2) ? (i == j)
       : (k == 3) ? ((i == 0 && j == 1) || (i == 1 && j == 0) || (i == 3 && j == 2) || (i == 2 && j == 3) || (i == 3 && j == 4) || (i == 4 && j == 3))
       :            ((i == 1 && j == 1) || (i == 3 && j == 3) || (i == 2 && j == 4) || (i == 4 && j == 2));
}
__host__ __device__ constexpr bool w3j_nz(int l1, int l2, int l3, int i, int j, int k) {
  return (l1 == 0) ? (j == k)
       : (l2 == 0) ? (i == k)
       : (l3 == 0) ? (i == j)
       : (l1 == 1 && l2 == 1 && l3 == 2) ? nz112(i, j, k)
       : (l1 == 1 && l2 == 2 && l3 == 1) ? nz112(i, k, j)
       : (l1 == 2 && l2 == 1 && l3 == 1) ? nz112(j, k, i)
       : nz222(i, j, k);
}
__host__ __device__ constexpr bool pair_used(int l1, int l2, int l3, int i, int j) {
  for (int k = 0; k < 2 * l3 + 1; ++k)
    if (w3j_nz(l1, l2, l3, i, j, k)) return true;
  return false;
}

// ---------------- prep: ws f32 -> f16 in MFMA B-fragment order ----------------
// wsf[((p*4 + nt)*128 + uk)*512 + lane*8 + j] = ws[p][uv = uk*32 + (lane>>4)*8 + j][w = nt*16 + (lane&15)]
__global__ void prep_ws(const float* __restrict__ ws, f16* __restrict__ wsf) {
  int blk = blockIdx.x;            // 11*128 blocks
  int p = blk >> 7, uk = blk & 127;
  int tid = threadIdx.x;           // 256
  int nt = tid >> 6, l = tid & 63;
  int w = nt * 16 + (l & 15);
  int uvb = uk * 32 + (l >> 4) * 8;
  f16x8 v;
#pragma unroll
  for (int j = 0; j < 8; ++j)
    v[j] = (f16)ws[(size_t)p * 262144 + (size_t)(uvb + j) * 64 + w];
  *(f16x8*)(wsf + ((size_t)((p * 4 + nt) * 128 + uk)) * 512 + (size_t)l * 8) = v;
}

// ---------------- main kernel ----------------
__device__ __forceinline__ f32x4 mfma16(f16x8 a, f16x8 b, f32x4 c) {
  return __builtin_amdgcn_mfma_f32_16x16x32_f16(a, b, c, 0, 0, 0);
}

template <int L1, int L2, int L3, int PORIG, int COFF, int J0, int JW>
__device__ __forceinline__ void run_chunk(
    const f16* __restrict__ x2buf, const f16* __restrict__ x1buf,
    const f16* __restrict__ wsf, const KC& kc,
    int lane, int nt, int bh, int uq, f32x4 (&o)[5]) {
  constexpr int d1 = 2 * L1 + 1, d2 = 2 * L2 + 1, d3 = 2 * L3 + 1;
  const int brow = lane >> 4, bcol = lane & 15;

  // pack A-fragments (x2) for jj in [J0, J0+JW)
  f16x8 afrag[JW][2];
#pragma unroll
  for (int jw = 0; jw < JW; ++jw)
#pragma unroll
    for (int ks = 0; ks < 2; ++ks)
#pragma unroll
      for (int j = 0; j < 8; ++j) {
        int v = ks * 32 + brow * 8 + j;
        afrag[jw][ks][j] = x2buf[(v * d2 + (J0 + jw)) * PAD2 + bh * 16 + bcol];
      }

  // G[i][jw] accumulates sum_u x1[u,i]*M_u[jw] in packed f16 (2 halves of 4 b-rows)
  f16x2 G[d1][JW][2];
#pragma unroll
  for (int i = 0; i < d1; ++i)
#pragma unroll
    for (int jw = 0; jw < JW; ++jw) {
      G[i][jw][0] = f16x2{(f16)0.f, (f16)0.f};
      G[i][jw][1] = f16x2{(f16)0.f, (f16)0.f};
    }

  const f16* wb = wsf + (((size_t)(PORIG * 4 + nt)) * 128 + (size_t)uq * 32) * 512 + (size_t)lane * 8;
  auto bfld = [&](int u, int ks) -> f16x8 {
    return *(const f16x8*)(wb + (size_t)(u * 2 + ks) * 512);
  };

  auto stepu = [&](int uu, f16x8 bf0, f16x8 bf1) {
    f32x4 M[JW];
#pragma unroll
    for (int jw = 0; jw < JW; ++jw) {
      f32x4 z{0.f, 0.f, 0.f, 0.f};
      M[jw] = mfma16(afrag[jw][0], bf0, z);
    }
#pragma unroll
    for (int jw = 0; jw < JW; ++jw)
      M[jw] = mfma16(afrag[jw][1], bf1, M[jw]);
    f16x2 Ml[JW], Mh[JW];
#pragma unroll
    for (int jw = 0; jw < JW; ++jw) {
      Ml[jw] = pkrtz(M[jw][0], M[jw][1]);
      Mh[jw] = pkrtz(M[jw][2], M[jw][3]);
    }
#pragma unroll
    for (int i = 0; i < d1; ++i) {
      f16x4 x4 = *(const f16x4*)&x1buf[((uq * 16 + uu) * d1 + i) * PAD1 + bh * 16 + brow * 4];
      f16x2 xl{x4[0], x4[1]}, xh{x4[2], x4[3]};
#pragma unroll
      for (int jw = 0; jw < JW; ++jw)
        if (pair_used(L1, L2, L3, i, J0 + jw)) {
          G[i][jw][0] += xl * Ml[jw];
          G[i][jw][1] += xh * Mh[jw];
        }
    }
  };

  f16x8 a0 = bfld(0, 0), a1 = bfld(0, 1);
  f16x8 c0 = bfld(1, 0), c1 = bfld(1, 1);
#pragma unroll 1
  for (int up = 0; up < 8; ++up) {
    stepu(2 * up, a0, a1);
    int ua = (up < 7) ? 2 * up + 2 : 0;
    a0 = bfld(ua, 0); a1 = bfld(ua, 1);
    stepu(2 * up + 1, c0, c1);
    int ub = (up < 7) ? 2 * up + 3 : 1;
    c0 = bfld(ub, 0); c1 = bfld(ub, 1);
  }

  // C-mix once per chunk: o[k3] += C[i,jj,k3] * G[i][jj]
#pragma unroll
  for (int i = 0; i < d1; ++i)
#pragma unroll
    for (int jw = 0; jw < JW; ++jw)
      if (pair_used(L1, L2, L3, i, J0 + jw)) {
        float g0 = (float)G[i][jw][0][0], g1 = (float)G[i][jw][0][1];
        float g2 = (float)G[i][jw][1][0], g3 = (float)G[i][jw][1][1];
#pragma unroll
        for (int k3 = 0; k3 < d3; ++k3)
          if (w3j_nz(L1, L2, L3, i, J0 + jw, k3)) {
            float cv = kc.c[COFF + (i * d2 + (J0 + jw)) * d3 + k3];
            o[k3][0] = fmaf(cv, g0, o[k3][0]);
            o[k3][1] = fmaf(cv, g1, o[k3][1]);
            o[k3][2] = fmaf(cv, g2, o[k3][2]);
            o[k3][3] = fmaf(cv, g3, o[k3][3]);
          }
      }
}

template <int L1, int L2, int L3, int PORIG, int COFF>
__device__ __forceinline__ void process_path(
    const float* __restrict__ x1, const float* __restrict__ x2,
    const f16* __restrict__ wsf, const KC& kc, f16* x2buf, f16* x1buf,
    int b0, int tid, int lane, int nt, int bh, int uq, f32x4 (&o)[5]) {
  constexpr int d1 = 2 * L1 + 1, d2 = 2 * L2 + 1;
  constexpr int OFF1 = (L1 == 0) ? 0 : (L1 == 1) ? 64 : 256;
  constexpr int OFF2 = (L2 == 0) ? 0 : (L2 == 1) ? 64 : 256;

  __syncthreads();  // prior readers of x1buf/x2buf/obuf done
#pragma unroll 1
  for (int idx = tid; idx < 2048 * d2; idx += 512) {
    int b = idx / (64 * d2), f = idx - b * (64 * d2);  // f = v*d2 + jj
    x2buf[f * PAD2 + b] = (f16)x2[(size_t)(b0 + b) * FEAT + OFF2 + f];
  }
#pragma unroll 1
  for (int idx = tid; idx < 2048 * d1; idx += 512) {
    int b = idx / (64 * d1), f = idx - b * (64 * d1);  // f = u*d1 + i
    x1buf[f * PAD1 + b] = (f16)x1[(size_t)(b0 + b) * FEAT + OFF1 + f];
  }
  __syncthreads();

  if constexpr (d2 == 1) {
    run_chunk<L1, L2, L3, PORIG, COFF, 0, 1>(x2buf, x1buf, wsf, kc, lane, nt, bh, uq, o);
  } else if constexpr (d2 == 3) {
    run_chunk<L1, L2, L3, PORIG, COFF, 0, 2>(x2buf, x1buf, wsf, kc, lane, nt, bh, uq, o);
    run_chunk<L1, L2, L3, PORIG, COFF, 2, 1>(x2buf, x1buf, wsf, kc, lane, nt, bh, uq, o);
  } else {
    run_chunk<L1, L2, L3, PORIG, COFF, 0, 2>(x2buf, x1buf, wsf, kc, lane, nt, bh, uq, o);
    run_chunk<L1, L2, L3, PORIG, COFF, 2, 2>(x2buf, x1buf, wsf, kc, lane, nt, bh, uq, o);
    run_chunk<L1, L2, L3, PORIG, COFF, 4, 1>(x2buf, x1buf, wsf, kc, lane, nt, bh, uq, o);
  }
}

template <int L3, int OFF3>
__device__ __forceinline__ void store_group(float* __restrict__ out, float* obuf,
                                            int b0, int lane, int nt, int bh, int uq,
                                            f32x4 (&o)[5]) {
  constexpr int d3 = 2 * L3 + 1;
  const int brow = lane >> 4, bcol = lane & 15;
  __syncthreads();  // all u-loop LDS reads done; obuf overlays x2buf/x1buf
  if (uq > 0) {
    float* s = obuf + (size_t)(uq - 1) * (512 * d3) + (size_t)bh * (256 * d3);
#pragma unroll
    for (int k3 = 0; k3 < d3; ++k3)
#pragma unroll
      for (int r = 0; r < 4; ++r)
        s[((brow * 4 + r) * 16 + bcol) * d3 + k3] = o[k3][r];
  }
  __syncthreads();
  if (uq == 0) {
#pragma unroll 1
    for (int q = 0; q < 3; ++q) {
      const float* s = obuf + (size_t)q * (512 * d3) + (size_t)bh * (256 * d3);
#pragma unroll
      for (int k3 = 0; k3 < d3; ++k3)
#pragma unroll
        for (int r = 0; r < 4; ++r)
          o[k3][r] += s[((brow * 4 + r) * 16 + bcol) * d3 + k3];
    }
#pragma unroll
    for (int k3 = 0; k3 < d3; ++k3)
#pragma unroll
      for (int r = 0; r < 4; ++r)
        out[(size_t)(b0 + bh * 16 + brow * 4 + r) * FEAT + OFF3 + (nt * 16 + bcol) * d3 + k3] = o[k3][r];
  }
#pragma unroll
  for (int k3 = 0; k3 < 5; ++k3) o[k3] = f32x4{0.f, 0.f, 0.f, 0.f};
}

__global__ __launch_bounds__(512, 4) void tp_main(
    const float* __restrict__ x1, const float* __restrict__ x2,
    const f16* __restrict__ wsf, float* __restrict__ out, KC kc) {
  __shared__ alignas(16) f16 smem[11200 + 11520];  // x2buf[320*35] + x1buf[320*36]
  f16* x2buf = smem;
  f16* x1buf = smem + 11200;
  float* obuf = (float*)smem;  // overlay, used only in store_group

  int tid = threadIdx.x;
  int lane = tid & 63, wave = tid >> 6;
  int bh = wave & 1, uq = wave >> 1;   // 8 waves = 2 bh x 4 u-quarters
  int blk = blockIdx.x;                // 512 blocks = 128 btiles x 4 nt
  int nt = blk & 3, btile = blk >> 2;
  int b0 = btile * 32;

  f32x4 o[5];
#pragma unroll
  for (int k = 0; k < 5; ++k) o[k] = f32x4{0.f, 0.f, 0.f, 0.f};

  // i3 = 0 group (out feats [0,64), d3=1)
  process_path<0, 0, 0, 0, 0>(x1, x2, wsf, kc, x2buf, x1buf, b0, tid, lane, nt, bh, uq, o);
  process_path<1, 1, 0, 4, 44>(x1, x2, wsf, kc, x2buf, x1buf, b0, tid, lane, nt, bh, uq, o);
  process_path<2, 2, 0, 9, 213>(x1, x2, wsf, kc, x2buf, x1buf, b0, tid, lane, nt, bh, uq, o);
  store_group<0, 0>(out, obuf, b0, lane, nt, bh, uq, o);
  // i3 = 1 group (out feats [64,256), d3=3)
  process_path<0, 1, 1, 1, 1>(x1, x2, wsf, kc, x2buf, x1buf, b0, tid, lane, nt, bh, uq, o);
  process_path<1, 0, 1, 3, 35>(x1, x2, wsf, kc, x2buf, x1buf, b0, tid, lane, nt, bh, uq, o);
  process_path<1, 2, 1, 6, 98>(x1, x2, wsf, kc, x2buf, x1buf, b0, tid, lane, nt, bh, uq, o);
  process_path<2, 1, 1, 8, 168>(x1, x2, wsf, kc, x2buf, x1buf, b0, tid, lane, nt, bh, uq, o);
  store_group<1, 64>(out, obuf, b0, lane, nt, bh, uq, o);
  // i3 = 2 group (out feats [256,576), d3=5)
  process_path<0, 2, 2, 2, 10>(x1, x2, wsf, kc, x2buf, x1buf, b0, tid, lane, nt, bh, uq, o);
  process_path<1, 1, 2, 5, 53>(x1, x2, wsf, kc, x2buf, x1buf, b0, tid, lane, nt, bh, uq, o);
  process_path<2, 0, 2, 7, 143>(x1, x2, wsf, kc, x2buf, x1buf, b0, tid, lane, nt, bh, uq, o);
  process_path<2, 2, 2, 10, 238>(x1, x2, wsf, kc, x2buf, x1buf, b0, tid, lane, nt, bh, uq, o);
  store_group<2, 256>(out, obuf, b0, lane, nt, bh, uq, o);
}

// ---------------- host: exact port of reference Wigner-3j construction ----------------
static double factd(int n) { double r = 1; for (int i = 2; i <= n; ++i) r *= i; return r; }

static double su2_cg(int j1, int j2, int j3, int m1, int m2, int m3) {
  if (m1 + m2 != m3) return 0.0;
  double pre = std::sqrt((2 * j3 + 1) * factd(j1 + j2 - j3) * factd(j1 - j2 + j3) * factd(-j1 + j2 + j3) / factd(j1 + j2 + j3 + 1));
  pre *= std::sqrt(factd(j3 + m3) * factd(j3 - m3) * factd(j1 - m1) * factd(j1 + m1) * factd(j2 - m2) * factd(j2 + m2));
  double s = 0.0;
  for (int v = 0; v <= j1 + j2 - j3; ++v) {
    int t[6] = {v, j1 + j2 - j3 - v, j1 - m1 - v, j2 + m2 - v, j3 - j2 + m1 + v, j3 - j1 - m2 + v};
    bool ok = true;
    for (int x = 0; x < 6; ++x) if (t[x] < 0) ok = false;
    if (!ok) continue;
    double den = 1.0;
    for (int x = 0; x < 6; ++x) den *= factd(t[x]);
    s += ((v & 1) ? -1.0 : 1.0) / den;
  }
  return pre * s;
}

static void qmat(int l, std::complex<double> q[5][5]) {
  int n = 2 * l + 1;
  for (int i = 0; i < 5; ++i) for (int j = 0; j < 5; ++j) q[i][j] = 0.0;
  const double s = 1.0 / std::sqrt(2.0);
  for (int m = -l; m < 0; ++m) {
    q[l + m][l - m] = s;
    q[l + m][l + m] = std::complex<double>(0.0, -s);
  }
  q[l][l] = 1.0;
  for (int m = 1; m <= l; ++m) {
    double sg = (m % 2) ? -1.0 : 1.0;
    q[l + m][l + m] = sg * s;
    q[l + m][l - m] = std::complex<double>(0.0, sg * s);
  }
  std::complex<double> pref(1.0, 0.0);
  for (int t = 0; t < l; ++t) pref *= std::complex<double>(0.0, -1.0);
  for (int i = 0; i < n; ++i) for (int j = 0; j < n; ++j) q[i][j] *= pref;
}

static void compute_w3j(int l1, int l2, int l3, float* dst) {
  int n1 = 2 * l1 + 1, n2 = 2 * l2 + 1, n3 = 2 * l3 + 1;
  std::complex<double> q1[5][5], q2[5][5], q3[5][5];
  qmat(l1, q1); qmat(l2, q2); qmat(l3, q3);
  double nrm = 0.0;
  double C[5][5][5];
  for (int a = 0; a < n1; ++a)
    for (int b = 0; b < n2; ++b)
      for (int c = 0; c < n3; ++c) {
        std::complex<double> acc(0.0, 0.0);
        for (int i = 0; i < n1; ++i)
          for (int j = 0; j < n2; ++j)
            for (int k = 0; k < n3; ++k) {
              double cg = su2_cg(l1, l2, l3, i - l1, j - l2, k - l3);
              if (cg != 0.0) acc += q1[i][a] * q2[j][b] * std::conj(q3[k][c]) * cg;
            }
        C[a][b][c] = acc.real();
        nrm += acc.real() * acc.real();
      }
  double inv = 1.0 / std::sqrt(nrm);
  for (int a = 0; a < n1; ++a)
    for (int b = 0; b < n2; ++b)
      for (int c = 0; c < n3; ++c)
        dst[(a * n2 + b) * n3 + c] = (float)(C[a][b][c] * inv);
}

extern "C" void kernel_launch(void* const* d_in, const int* in_sizes, int n_in,
                              void* d_out, int out_size, void* d_ws, size_t ws_size,
                              hipStream_t stream) {
  const float* x1 = (const float*)d_in[0];
  const float* x2 = (const float*)d_in[1];
  const float* ws = (const float*)d_in[2];
  float* out = (float*)d_out;
  f16* wsf = (f16*)d_ws;

  KC kc;
  {
    static const int L1[11] = {0, 0, 0, 1, 1, 1, 1, 2, 2, 2, 2};
    static const int L2[11] = {0, 1, 2, 0, 1, 1, 2, 0, 1, 2, 2};
    static const int L3[11] = {0, 1, 2, 1, 0, 2, 1, 2, 1, 0, 2};
    static const int COFFS[11] = {0, 1, 10, 35, 44, 53, 98, 143, 168, 213, 238};
    for (int p = 0; p < 11; ++p) compute_w3j(L1[p], L2[p], L3[p], kc.c + COFFS[p]);
  }

  hipLaunchKernelGGL(prep_ws, dim3(11 * 128), dim3(256), 0, stream, ws, wsf);
  hipLaunchKernelGGL(tp_main, dim3(512), dim3(512), 0, stream, x1, x2, wsf, out, kc);
}